// Round 4
// baseline (133.826 us; speedup 1.0000x reference)
//
#include <hip/hip_runtime.h>

#define MARGIN 0.3f

typedef __attribute__((ext_vector_type(8))) short short8;
typedef __attribute__((ext_vector_type(4))) short short4v;
typedef __attribute__((ext_vector_type(4))) float floatx4;

// address-space casts for global_load_lds (direct global->LDS DMA)
#define AS_GLOBAL(p) ((const __attribute__((address_space(1))) char*)(p))
#define AS_LDS(p)    ((__attribute__((address_space(3))) char*)(p))

// ---- helpers ----------------------------------------------------------------

// order-preserving float->uint encoding so unsigned atomicMin == float min
__device__ __forceinline__ unsigned enc_f32(float f) {
    unsigned u = __float_as_uint(f);
    return (u & 0x80000000u) ? ~u : (u | 0x80000000u);
}
__device__ __forceinline__ float dec_f32(unsigned u) {
    return (u & 0x80000000u) ? __uint_as_float(u & 0x7fffffffu)
                             : __uint_as_float(~u);
}
// fp32 -> bf16 bits, round-to-nearest-even
__device__ __forceinline__ short f2bf(float f) {
    unsigned u = __float_as_uint(f);
    u = u + 0x7fffu + ((u >> 16) & 1u);
    return (short)(u >> 16);
}

// ---- kernel 1: prepass ------------------------------------------------------
// fp32 -> bf16 with the LDS XOR swizzle baked into the GLOBAL layout:
// element (row, c): granule g=c/8 stored at row*128 + (g^(row&15))*8 + c%8.
// Also: sq2[row] (exact fp32), rowmin init, per-rowtile counter init.
__global__ void prep_kernel(const float* __restrict__ z1, const float* __restrict__ z2,
                            short* __restrict__ z1b, short* __restrict__ z2b,
                            float* __restrict__ sq2, unsigned* __restrict__ rowmin,
                            unsigned* __restrict__ cnt) {
    int idx = blockIdx.x * 256 + threadIdx.x;   // float4 index, 32 per row
    int row = idx >> 5;
    int c4  = idx & 31;
    int g   = c4 >> 1;                          // 16B granule (8 bf16)
    int slot = ((g ^ (row & 15)) << 3) + ((c4 & 1) << 2);
    float4 fa = ((const float4*)z1)[idx];
    float4 fb = ((const float4*)z2)[idx];
    short4v sa = { f2bf(fa.x), f2bf(fa.y), f2bf(fa.z), f2bf(fa.w) };
    short4v sb = { f2bf(fb.x), f2bf(fb.y), f2bf(fb.z), f2bf(fb.w) };
    *(short4v*)&z1b[(size_t)row * 128 + slot] = sa;
    *(short4v*)&z2b[(size_t)row * 128 + slot] = sb;
    float s = fb.x * fb.x + fb.y * fb.y + fb.z * fb.z + fb.w * fb.w;
    #pragma unroll
    for (int m = 16; m >= 1; m >>= 1) s += __shfl_xor(s, m);
    if (c4 == 0) sq2[row] = s;
    if (threadIdx.x < 8) rowmin[blockIdx.x * 8 + threadIdx.x] = 0xFFFFFFFFu;
    if (blockIdx.x == 0 && threadIdx.x < 64) cnt[threadIdx.x] = 0u;
}

// ---- kernel 2: persistent-A GEMM + row-min + fused loss ---------------------
// grid (8, 64): blockIdx.y = rt (128-row tile), blockIdx.x = cg (1024-col group
// = 16 tiles of 64 cols). 512 blocks = 2/CU. LDS: A 32 KB + B dbuf 2x16 KB.
// A fragments hoisted to registers; B double-buffered via global_load_lds.
// Last block to finish a row-tile computes the loss for its 128 rows.
__global__ __launch_bounds__(256, 2)
void gemm_min_kernel(const short* __restrict__ z1b, const short* __restrict__ z2b,
                     const float* __restrict__ sq2,
                     const float* __restrict__ z1, const float* __restrict__ z2,
                     unsigned* __restrict__ rowmin, unsigned* __restrict__ cnt,
                     float* __restrict__ out, int n)
{
    __shared__ short As[128 * 128];        // 32 KB, free after A-frag hoist
    __shared__ short Bs[2][64 * 128];      // 2 x 16 KB
    __shared__ float lsum[4];
    __shared__ int   fin;

    const int rt = blockIdx.y, cg = blockIdx.x;
    const int tid = threadIdx.x;

    const short* gA = z1b + (size_t)rt * 16384;          // 32 KB tile (swizzled)
    const short* gB = z2b + (size_t)cg * (1024 * 128);   // this block's 256 KB

    // stage A (8 x 16B/lane) + B0 (4 x 16B/lane); flat linear DMA copies
    #pragma unroll
    for (int it = 0; it < 8; ++it) {
        int off = it * 2048 + tid * 8;
        __builtin_amdgcn_global_load_lds(AS_GLOBAL(gA + off), AS_LDS(As + off), 16, 0, 0);
    }
    #pragma unroll
    for (int it = 0; it < 4; ++it) {
        int off = it * 2048 + tid * 8;
        __builtin_amdgcn_global_load_lds(AS_GLOBAL(gB + off), AS_LDS(&Bs[0][0] + off), 16, 0, 0);
    }

    const int w = tid >> 6, lane = tid & 63;
    const int quad = lane >> 4, l15 = lane & 15;
    const int wr = w * 32;               // wave owns rows [wr, wr+32) of the tile

    __syncthreads();                     // DMA complete

    // hoist A fragments: A[m = l15 + sm*16 + wr][k = quad*8 .. +7 + kk*32]
    short8 af[2][4];
    #pragma unroll
    for (int sm = 0; sm < 2; ++sm) {
        int ra = wr + sm * 16 + l15;     // ra & 15 == l15
        #pragma unroll
        for (int kk = 0; kk < 4; ++kk) {
            int g16 = kk * 4 + quad;
            af[sm][kk] = *(const short8*)&As[ra * 128 + ((g16 ^ l15) << 3)];
        }
    }

    float vmin[2][4];
    #pragma unroll
    for (int sm = 0; sm < 2; ++sm)
        #pragma unroll
        for (int reg = 0; reg < 4; ++reg)
            vmin[sm][reg] = 3.0e38f;

    for (int t = 0; t < 16; ++t) {
        // prefetch next B tile into the other buffer (overlaps MFMAs below)
        if (t < 15) {
            const short* gBn = gB + (t + 1) * 8192;     // 64 rows x 128 shorts
            short* dst = &Bs[(t + 1) & 1][0];
            #pragma unroll
            for (int it = 0; it < 4; ++it) {
                int off = it * 2048 + tid * 8;
                __builtin_amdgcn_global_load_lds(AS_GLOBAL(gBn + off), AS_LDS(dst + off), 16, 0, 0);
            }
        }
        const short* Bt = &Bs[t & 1][0];
        const int colbase = cg * 1024 + t * 64;

        float s2[4];
        #pragma unroll
        for (int sn = 0; sn < 4; ++sn)
            s2[sn] = sq2[colbase + sn * 16 + l15];

        floatx4 acc[2][4];
        #pragma unroll
        for (int sm = 0; sm < 2; ++sm)
            #pragma unroll
            for (int sn = 0; sn < 4; ++sn)
                acc[sm][sn] = (floatx4)0.0f;

        #pragma unroll
        for (int kk = 0; kk < 4; ++kk) {
            const int g16 = kk * 4 + quad;
            short8 bfr[4];
            #pragma unroll
            for (int sn = 0; sn < 4; ++sn) {
                int rb = sn * 16 + l15;  // rb & 15 == l15
                bfr[sn] = *(const short8*)&Bt[rb * 128 + ((g16 ^ l15) << 3)];
            }
            #pragma unroll
            for (int sm = 0; sm < 2; ++sm)
                #pragma unroll
                for (int sn = 0; sn < 4; ++sn)
                    acc[sm][sn] = __builtin_amdgcn_mfma_f32_16x16x32_bf16(
                        af[sm][kk], bfr[sn], acc[sm][sn], 0, 0, 0);
        }

        // fold row-min into registers: v = sq2[j] - 2*dot, diagonal -> +inf
        #pragma unroll
        for (int sm = 0; sm < 2; ++sm) {
            #pragma unroll
            for (int reg = 0; reg < 4; ++reg) {
                int gi = rt * 128 + wr + sm * 16 + quad * 4 + reg;
                #pragma unroll
                for (int sn = 0; sn < 4; ++sn) {
                    int gj = colbase + sn * 16 + l15;
                    float v = fmaf(-2.0f, acc[sm][sn][reg], s2[sn]);
                    v = (gi == gj) ? 3.0e38f : v;
                    vmin[sm][reg] = fminf(vmin[sm][reg], v);
                }
            }
        }
        __syncthreads();   // drains prefetch DMA; next iter reads other buffer
    }

    // cross-lane (quad) min + one atomicMin per row
    #pragma unroll
    for (int sm = 0; sm < 2; ++sm) {
        #pragma unroll
        for (int reg = 0; reg < 4; ++reg) {
            float vm = vmin[sm][reg];
            #pragma unroll
            for (int m = 8; m >= 1; m >>= 1)
                vm = fminf(vm, __shfl_xor(vm, m));
            if (l15 == 0)
                atomicMin(&rowmin[rt * 128 + wr + sm * 16 + quad * 4 + reg], enc_f32(vm));
        }
    }

    __syncthreads();       // all this block's atomicMins drained (vmcnt(0))
    if (tid == 0) {
        __threadfence();   // release: mins visible before counter bump
        fin = (atomicAdd(&cnt[rt], 1u) == 7u);
    }
    __syncthreads();
    if (!fin) return;
    __threadfence();       // acquire: see all 8 blocks' mins

    // fused loss for rows [rt*128, rt*128+128): exact fp32 pos-dist
    float* shmin = (float*)As;           // As is free (A frags in registers)
    if (tid < 128) {
        // device-scope atomic read (atomicMin with UINT_MAX never modifies)
        unsigned rm = atomicMin(&rowmin[rt * 128 + tid], 0xFFFFFFFFu);
        shmin[tid] = dec_f32(rm);
    }
    __syncthreads();

    float acc_loss = 0.0f;
    for (int k = 0; k < 32; ++k) {       // wave w: rows w*32 .. w*32+31
        int r = w * 32 + k;
        int i = rt * 128 + r;
        const float* p1 = z1 + (size_t)i * 128;
        const float* p2 = z2 + (size_t)i * 128;
        float a0 = p1[lane], a1 = p1[lane + 64];
        float b0 = p2[lane], b1 = p2[lane + 64];
        float d0 = a0 - b0, d1 = a1 - b1;
        float pos2 = d0 * d0 + d1 * d1;
        float s1   = a0 * a0 + a1 * a1;
        #pragma unroll
        for (int m = 32; m >= 1; m >>= 1) {
            pos2 += __shfl_xor(pos2, m);
            s1   += __shfl_xor(s1, m);
        }
        if (lane == 0) {
            float neg2 = s1 + shmin[r];
            float hard = sqrtf(fmaxf(neg2, 0.0f));
            float pos  = sqrtf(fmaxf(pos2, 0.0f));
            acc_loss += fmaxf(pos - hard + MARGIN, 0.0f);
        }
    }
    if (lane == 0) lsum[w] = acc_loss;
    __syncthreads();
    if (tid == 0)
        atomicAdd(out, (lsum[0] + lsum[1] + lsum[2] + lsum[3]) / (float)n);
}

// ---- launch -----------------------------------------------------------------
extern "C" void kernel_launch(void* const* d_in, const int* in_sizes, int n_in,
                              void* d_out, int out_size, void* d_ws, size_t ws_size,
                              hipStream_t stream) {
    const float* z1 = (const float*)d_in[0];
    const float* z2 = (const float*)d_in[1];
    const int n = in_sizes[0] / 128;            // 8192

    char* ws = (char*)d_ws;
    short*    z1b    = (short*)ws;                                   // 2 MB
    short*    z2b    = (short*)(ws + (size_t)n * 128 * 2);           // 2 MB
    float*    sq2    = (float*)(ws + (size_t)n * 128 * 4);           // 32 KB
    unsigned* rowmin = (unsigned*)(ws + (size_t)n * 128 * 4 + n * 4);// 32 KB
    unsigned* cnt    = (unsigned*)(ws + (size_t)n * 128 * 4 + n * 8);// 256 B
    float*    out    = (float*)d_out;

    hipMemsetAsync(out, 0, sizeof(float), stream);   // accumulated via atomics
    prep_kernel<<<n * 32 / 256, 256, 0, stream>>>(z1, z2, z1b, z2b, sq2, rowmin, cnt);
    dim3 grid(8, n / 128);                           // (colgroups, row tiles)
    gemm_min_kernel<<<grid, 256, 0, stream>>>(z1b, z2b, sq2, z1, z2,
                                              rowmin, cnt, out, n);
}